// Round 10
// baseline (236.215 us; speedup 1.0000x reference)
//
#include <hip/hip_runtime.h>
#include <hip/hip_bf16.h>

#define N_NODES 50000
#define N_PER   12500
#define E_EDGES 600000
#define HDIM    128

#define NBLK_FC    ((N_PER + 63) / 64)            // 196
#define NBLK_NODE  ((N_NODES + 255) / 256)        // 196
#define MASK31  0x7fffffff

// counting-sort tiling: zero device atomics anywhere.
#define HQD 64                   // edge slices (single fused histogram pass)
#define HSL_D (E_EDGES / HQD)    // 9375
#define NBLK_DB (HQD * 4)        // 256 scatter/hist blocks

typedef __attribute__((ext_vector_type(8))) short bfrag;   // 8 bf16 (4 VGPRs)
typedef __attribute__((ext_vector_type(4))) float ffrag;   // 4 fp32 acc

__device__ __forceinline__ unsigned short f2bf(float f) {
    union { float f; unsigned u; } x; x.f = f;
    unsigned r = x.u + 0x7fffu + ((x.u >> 16) & 1u);   // RTNE
    return (unsigned short)(r >> 16);
}
__device__ __forceinline__ float lo_bf(unsigned v) { return __uint_as_float(v << 16); }
__device__ __forceinline__ float hi_bf(unsigned v) { return __uint_as_float(v & 0xffff0000u); }
__device__ __forceinline__ unsigned pack2(float a, float b) {
    return (unsigned)f2bf(a) | ((unsigned)f2bf(b) << 16);
}
__device__ __forceinline__ float onrm_of(int deg) {
    return rsqrtf(fmaxf((float)deg, 1.0f));
}

__device__ __forceinline__ void acc8_add(float* acc, uint4 v) {
    acc[0] += lo_bf(v.x); acc[1] += hi_bf(v.x);
    acc[2] += lo_bf(v.y); acc[3] += hi_bf(v.y);
    acc[4] += lo_bf(v.z); acc[5] += hi_bf(v.z);
    acc[6] += lo_bf(v.w); acc[7] += hi_bf(v.w);
}
__device__ __forceinline__ void acc8_addw(float* acc, uint4 v, float w) {
    acc[0] += lo_bf(v.x) * w; acc[1] += hi_bf(v.x) * w;
    acc[2] += lo_bf(v.y) * w; acc[3] += hi_bf(v.y) * w;
    acc[4] += lo_bf(v.z) * w; acc[5] += hi_bf(v.z) * w;
    acc[6] += lo_bf(v.w) * w; acc[7] += hi_bf(v.w) * w;
}

// ---------------------------------------------------------------------------
// K0 prep (1024 threads):
//   blocks [0,256):   fused histogram — ONE packed uint32 plane array:
//                     D (bits 0..9) | B (10..15) | S (16..31).
//   blocks [256,264): weight fragment packing
// ---------------------------------------------------------------------------
__global__ __launch_bounds__(1024) void prep_kernel(
    const float* __restrict__ W0, const float* __restrict__ W1,
    const float* __restrict__ W2, const float* __restrict__ W3,
    const float* __restrict__ Wg,
    const int* __restrict__ src, const int* __restrict__ dst,
    const int* __restrict__ ef,
    unsigned short* __restrict__ Wp,
    unsigned* __restrict__ partial) {
    __shared__ unsigned hist[N_PER];            // 50 KB
    int b = blockIdx.x;
    if (b < NBLK_DB) {                          // fused D|B|S histogram
        const int q = b >> 2;
        const int p = b & 3;
        const int g0 = p * N_PER;
        for (int j = threadIdx.x; j < N_PER; j += 1024) hist[j] = 0;
        __syncthreads();
        const int e0 = q * HSL_D;
        for (int i = e0 + threadIdx.x; i < e0 + HSL_D; i += 1024) {
            int d = dst[i], t = ef[i], s = src[i];
            unsigned rd = (unsigned)(d - g0);
            if (rd < (unsigned)N_PER) atomicAdd(&hist[rd], 1u);
            unsigned rs = (unsigned)(s - g0);
            if (rs < (unsigned)N_PER) {
                unsigned inc = 0x10000u
                             + ((t == 6 || t == 14 || t == 30) ? 0x400u : 0u);
                atomicAdd(&hist[rs], inc);
            }
        }
        __syncthreads();
        for (int j = threadIdx.x; j < N_PER; j += 1024)
            partial[(size_t)q * N_NODES + g0 + j] = hist[j];
    } else {                                    // weight packing
        int tid = (b - NBLK_DB) * 1024 + threadIdx.x;   // [0, 8192)
        const float* W; int D, base, off;
        if      (tid < 2048) { W = W0; D = 128; base = 0;    off = 0;     }
        else if (tid < 4096) { W = W1; D = 128; base = 2048; off = 16384; }
        else if (tid < 5120) { W = W2; D = 64;  base = 4096; off = 32768; }
        else if (tid < 6144) { W = W3; D = 64;  base = 5120; off = 40960; }
        else                 { W = Wg; D = 128; base = 6144; off = 49152; }
        int t2 = tid - base;
        int KT = D / 32;
        int l = t2 & 63;
        int tt = t2 >> 6;
        int kt = tt % KT, n0 = tt / KT;
        int n = n0 * 16 + (l & 15);
        int kb = kt * 32 + (l >> 4) * 8;
#pragma unroll
        for (int j = 0; j < 8; ++j)
            Wp[(size_t)off + (size_t)t2 * 8 + j] = f2bf(W[(size_t)(kb + j) * 128 + n]);
    }
}

// ---------------------------------------------------------------------------
// P1: ONE pass over the 64 packed planes -> per-slice prefixes (in place),
//     degD/degB, onrm_buf, 16B-aligned block-local scan, block sums,
//     AND per-block 64-bin degree histogram -> binpartT[bin][block]
//     (for the degree-sorted gather permutation).
// ---------------------------------------------------------------------------
__global__ __launch_bounds__(256) void plane_prefix_kernel(
    unsigned* __restrict__ partial,
    int* __restrict__ degD, int* __restrict__ degB,
    int* __restrict__ scanD, int* __restrict__ scanB,
    int* __restrict__ blocksumD, int* __restrict__ blocksumB,
    float* __restrict__ onrm_buf,
    int* __restrict__ binpartT) {
    __shared__ int sD[256], sB[256];
    __shared__ unsigned binh[64];
    const int t = threadIdx.x;
    const int n = blockIdx.x * 256 + t;
    if (t < 64) binh[t] = 0;
    __syncthreads();
    int dA = 0, dD = 0, dB = 0;
    if (n < N_NODES) {
        int runD = 0, runB = 0, dS = 0;
#pragma unroll
        for (int q = 0; q < HQD; ++q) {
            size_t ix = (size_t)q * N_NODES + n;
            unsigned w = partial[ix];
            partial[ix] = (unsigned)runD | ((unsigned)runB << 10);
            runD += (int)(w & 0x3FFu);
            runB += (int)((w >> 10) & 0x3Fu);
            dS   += (int)(w >> 16);
        }
        dD = runD; dB = runB;
        degD[n] = dD; degB[n] = dB;
        onrm_buf[n] = onrm_of(dS);
        dA = (dD + 3) & ~3;                      // 16B-aligned segment size
        atomicAdd(&binh[min(dD, 63)], 1u);       // degree-bin count
    }
    sD[t] = dA; sB[t] = dB;
    __syncthreads();
    for (int off = 1; off < 256; off <<= 1) {     // Hillis-Steele inclusive
        int xD = (t >= off) ? sD[t - off] : 0;
        int xB = (t >= off) ? sB[t - off] : 0;
        __syncthreads();
        sD[t] += xD; sB[t] += xB;
        __syncthreads();
    }
    if (n < N_NODES) {
        scanD[n] = sD[t] - dA;                    // block-local exclusive
        scanB[n] = sB[t] - dB;
    }
    if (t == 255) {
        blocksumD[blockIdx.x] = sD[255];
        blocksumB[blockIdx.x] = sB[255];
    }
    if (t < 64)
        binpartT[t * NBLK_NODE + blockIdx.x] = (int)binh[t];
}

// ---------------------------------------------------------------------------
// P2: add block bases -> csrD/csrB, AND build the degree-sorted permutation:
//     each block redundantly derives its (bin,block) global offsets from
//     binpartT (64 lanes x 49 int4 sequential loads, L2-hot), then assigns
//     perm slots via LDS-atomic ranks. Any intra-bin order is a valid perm.
// ---------------------------------------------------------------------------
__global__ __launch_bounds__(256) void base_add_kernel(
    const int* __restrict__ blocksumD, const int* __restrict__ blocksumB,
    const int* __restrict__ scanD, const int* __restrict__ scanB,
    const int* __restrict__ degD, const int* __restrict__ degB,
    const int* __restrict__ binpartT,
    int2* __restrict__ csrD, int2* __restrict__ csrB,
    int* __restrict__ perm) {
    __shared__ int sD[256], sB[256];
    __shared__ int binfull[64], binpart_[64], binbase[64];
    __shared__ unsigned binh[64];
    const int t = threadIdx.x;
    const int bid = blockIdx.x;
    sD[t] = (t < bid) ? blocksumD[t] : 0;
    sB[t] = (t < bid) ? blocksumB[t] : 0;
    __syncthreads();
    for (int off = 128; off >= 1; off >>= 1) {
        if (t < off) { sD[t] += sD[t + off]; sB[t] += sB[t + off]; }
        __syncthreads();
    }
    // degree-bin offsets: column sums of binpartT (196 = 49*4 ints per bin)
    if (t < 64) {
        binh[t] = 0;
        int cf = 0, cp = 0;
        const int4* bp = (const int4*)(binpartT + t * NBLK_NODE);
#pragma unroll 8
        for (int j4 = 0; j4 < 49; ++j4) {
            int4 v = bp[j4];
            int bj = j4 * 4;
            cf += v.x + v.y + v.z + v.w;
            cp += ((bj     < bid) ? v.x : 0) + ((bj + 1 < bid) ? v.y : 0)
                + ((bj + 2 < bid) ? v.z : 0) + ((bj + 3 < bid) ? v.w : 0);
        }
        binfull[t] = cf; binpart_[t] = cp;
    }
    __syncthreads();
    if (t == 0) {
        int run = 0;
        for (int bb = 0; bb < 64; ++bb) {
            int c = binfull[bb]; binfull[bb] = run; run += c;
        }
    }
    __syncthreads();
    if (t < 64) binbase[t] = binfull[t] + binpart_[t];
    __syncthreads();
    const int n = bid * 256 + t;
    if (n < N_NODES) {
        csrD[n] = make_int2(scanD[n] + sD[0], degD[n]);
        csrB[n] = make_int2(scanB[n] + sB[0], degB[n]);
        int bin = min(degD[n], 63);
        unsigned rank = atomicAdd(&binh[bin], 1u);
        perm[binbase[bin] + (int)rank] = n;
    }
}

// ---------------------------------------------------------------------------
// FC MFMA body: out = bf16( (X(rows x D) @ W + bias) * onrm[row] ); X fp32.
// tid must be in [0,256). No LDS, no sync — safe inside mixed blocks.
// ---------------------------------------------------------------------------
template<int D>
__device__ __forceinline__ void fc_body(
    int blk, int tid,
    const float* __restrict__ X,
    const unsigned short* __restrict__ Wp,
    const float* __restrict__ bias,
    const float* __restrict__ onrm,
    unsigned short* __restrict__ outbf,
    int rows)
{
    constexpr int KT = D / 32;
    const int lane = tid & 63;
    const int wave = tid >> 6;
    const int m = lane & 15, q = lane >> 4;
    const int rbase = blk * 64 + wave * 16;
    const int row = rbase + m;

    bfrag afr[KT];
#pragma unroll
    for (int kt = 0; kt < KT; ++kt) {
        bfrag a;
        if (row < rows) {
            const float* xp = X + (size_t)row * D + kt * 32 + q * 8;
            float4 u0 = *(const float4*)xp;
            float4 u1 = *(const float4*)(xp + 4);
            a[0] = (short)f2bf(u0.x); a[1] = (short)f2bf(u0.y);
            a[2] = (short)f2bf(u0.z); a[3] = (short)f2bf(u0.w);
            a[4] = (short)f2bf(u1.x); a[5] = (short)f2bf(u1.y);
            a[6] = (short)f2bf(u1.z); a[7] = (short)f2bf(u1.w);
        } else {
#pragma unroll
            for (int t = 0; t < 8; ++t) a[t] = 0;
        }
        afr[kt] = a;
    }

    ffrag acc[8];
#pragma unroll
    for (int n0 = 0; n0 < 8; ++n0)
#pragma unroll
        for (int t = 0; t < 4; ++t) acc[n0][t] = 0.f;

#pragma unroll
    for (int n0 = 0; n0 < 8; ++n0)
#pragma unroll
        for (int kt = 0; kt < KT; ++kt) {
            bfrag bfr = *(const bfrag*)(Wp + ((size_t)(n0 * KT + kt) * 64 + lane) * 8);
            acc[n0] = __builtin_amdgcn_mfma_f32_16x16x32_bf16(afr[kt], bfr, acc[n0], 0, 0, 0);
        }

#pragma unroll
    for (int n0 = 0; n0 < 8; ++n0) {
        const int col = n0 * 16 + m;
        const float bj = bias[col];
#pragma unroll
        for (int r = 0; r < 4; ++r) {
            int orow = rbase + q * 4 + r;
            if (orow < rows)
                outbf[(size_t)orow * 128 + col] =
                    f2bf((acc[n0][r] + bj) * onrm[orow]);
        }
    }
}

// ---------------------------------------------------------------------------
// K1: fused scatter + FC. 1024-thread blocks.
//   blocks [0,256):   counting-sort scatter (LDS atomics, 50 KB offP;
//                     offP = abs 16B-aligned D slot (20b) | relB (12b))
//   blocks [256,452): 4 FC 64-row tiles each (tid>>8 selects tile).
// ---------------------------------------------------------------------------
__global__ __launch_bounds__(1024) void scatfc_kernel(
    const int* __restrict__ src, const int* __restrict__ dst,
    const int* __restrict__ ef,
    const unsigned* __restrict__ partial,
    const int2* __restrict__ csrD, const int2* __restrict__ csrB,
    int* __restrict__ bucket, int* __restrict__ bucketB,
    const float* __restrict__ f0, const float* __restrict__ f1,
    const float* __restrict__ f2, const float* __restrict__ f3,
    const unsigned short* __restrict__ Wp,
    const float* __restrict__ b0, const float* __restrict__ b1,
    const float* __restrict__ b2, const float* __restrict__ b3,
    const float* __restrict__ onrm_buf,
    unsigned short* __restrict__ Abf)
{
    __shared__ unsigned offP[N_PER];   // absD (20b) | relB (12b)
    const int b = blockIdx.x;
    if (b < NBLK_DB) {
        const int q = b >> 2;
        const int p = b & 3;
        const int g0 = p * N_PER;
        for (int j = threadIdx.x; j < N_PER; j += 1024) {
            unsigned w = partial[(size_t)q * N_NODES + g0 + j];
            offP[j] = (unsigned)(csrD[g0 + j].x + (int)(w & 0x3FFu))
                    | (((w >> 10) & 0x3Fu) << 20);
        }
        __syncthreads();
        const int e0 = q * HSL_D;
        for (int i = e0 + threadIdx.x; i < e0 + HSL_D; i += 1024) {
            int s = src[i], d = dst[i], t = ef[i];
            unsigned rd = (unsigned)(d - g0);
            if (rd < (unsigned)N_PER) {
                unsigned old = atomicAdd(&offP[rd], 1u);          // LDS atomic
                bucket[old & 0xFFFFFu] = s | ((t <= 4) ? 0x80000000 : 0);
            }
            if (t == 6 || t == 14 || t == 30) {
                unsigned rs = (unsigned)(s - g0);
                if (rs < (unsigned)N_PER) {
                    unsigned old = atomicAdd(&offP[rs], 1u << 20);
                    bucketB[csrB[s].x + (int)(old >> 20)] = d;
                }
            }
        }
    } else {
        int ft = (b - NBLK_DB) * 4 + (threadIdx.x >> 8);   // 0..783
        int tid = threadIdx.x & 255;
        int which = ft / NBLK_FC;
        int blk = ft - which * NBLK_FC;
        if (which == 0)
            fc_body<128>(blk, tid, f0, Wp,         b0, onrm_buf,
                         Abf + (size_t)0 * N_PER * HDIM, N_PER);
        else if (which == 1)
            fc_body<128>(blk, tid, f1, Wp + 16384, b1, onrm_buf + N_PER,
                         Abf + (size_t)1 * N_PER * HDIM, N_PER);
        else if (which == 2)
            fc_body<64>(blk, tid, f2, Wp + 32768, b2, onrm_buf + 2 * N_PER,
                        Abf + (size_t)2 * N_PER * HDIM, N_PER);
        else
            fc_body<64>(blk, tid, f3, Wp + 40960, b3, onrm_buf + 3 * N_PER,
                        Abf + (size_t)3 * N_PER * HDIM, N_PER);
    }
}

// ---------------------------------------------------------------------------
// Gather core: 16B-aligned CSR base -> int4 index loads (2 per 8 edges).
// ---------------------------------------------------------------------------
#define GATHER8(DSTARR)                                                       \
    for (; i + 8 <= cnt; i += 8) {                                            \
        int4 c0 = *(const int4*)(bk + i);                                     \
        int4 c1 = *(const int4*)(bk + i + 4);                                 \
        int cc[8] = {c0.x, c0.y, c0.z, c0.w, c1.x, c1.y, c1.z, c1.w};         \
        uint4 v[8];                                                           \
        _Pragma("unroll")                                                     \
        for (int k = 0; k < 8; ++k)                                           \
            v[k] = DSTARR[(size_t)(cc[k] & MASK31) * 16 + j8];                \
        _Pragma("unroll")                                                     \
        for (int k = 0; k < 8; ++k) acc8_add(acc, v[k]);                      \
    }                                                                         \
    if (i + 4 <= cnt) {                                                       \
        int4 c0 = *(const int4*)(bk + i);                                     \
        int cc[4] = {c0.x, c0.y, c0.z, c0.w};                                 \
        uint4 v[4];                                                           \
        _Pragma("unroll")                                                     \
        for (int k = 0; k < 4; ++k)                                           \
            v[k] = DSTARR[(size_t)(cc[k] & MASK31) * 16 + j8];                \
        _Pragma("unroll")                                                     \
        for (int k = 0; k < 4; ++k) acc8_add(acc, v[k]);                      \
        i += 4;                                                               \
    }                                                                         \
    for (; i < cnt; ++i)                                                      \
        acc8_add(acc, DSTARR[(size_t)(bk[i] & MASK31) * 16 + j8]);

// ---------------------------------------------------------------------------
// K3: FUSED layer-0 gather + dense GEMM with W_g1 (agg/matmul commute).
//   Block = 16 deg-sorted nodes (via perm): waves have uniform edge counts.
//   Writes BW = B @ W_g1 directly (rows scattered through pnode).
// ---------------------------------------------------------------------------
__global__ __launch_bounds__(256) void agg0g_kernel(
    const uint4* __restrict__ A,
    const int* __restrict__ bucket, const int2* __restrict__ csrD,
    const float* __restrict__ onrm_buf, const float* __restrict__ b_g0,
    const unsigned short* __restrict__ Wp,
    const int* __restrict__ perm,
    unsigned short* __restrict__ BW) {
    __shared__ uint4 Bt[256];          // 4 KB: idx = j8*16 + node_local
    __shared__ int pnode[16];
    const int tdx = threadIdx.x;
    const int nloc = tdx >> 4, j8 = tdx & 15;
    const int n = perm[blockIdx.x * 16 + nloc];
    if (tdx < 16) pnode[tdx] = perm[blockIdx.x * 16 + tdx];

    const int2 cd = csrD[n];
    const int cnt = cd.y;
    const int* bk = bucket + cd.x;
    float acc[8] = {0.f, 0.f, 0.f, 0.f, 0.f, 0.f, 0.f, 0.f};
    int i = 0;
    GATHER8(A)

    float inr = onrm_of(cnt);
    float onr = onrm_buf[n];
    const float* bg = b_g0 + j8 * 8;
    float r[8];
#pragma unroll
    for (int k = 0; k < 8; ++k)
        r[k] = fmaxf(acc[k] * inr + bg[k], 0.f) * onr;
    uint4 o;
    o.x = pack2(r[0], r[1]); o.y = pack2(r[2], r[3]);
    o.z = pack2(r[4], r[5]); o.w = pack2(r[6], r[7]);
    Bt[j8 * 16 + nloc] = o;
    __syncthreads();

    // MFMA phase: wave w -> col tiles n0 = 2w, 2w+1
    const int lane = tdx & 63;
    const int wave = tdx >> 6;
    const int m = lane & 15, q = lane >> 4;

    bfrag afr[4];
#pragma unroll
    for (int kt = 0; kt < 4; ++kt)
        afr[kt] = *(const bfrag*)(Bt + (kt * 4 + q) * 16 + m);

    ffrag acc2[2];
#pragma unroll
    for (int t2 = 0; t2 < 2; ++t2) {
#pragma unroll
        for (int t = 0; t < 4; ++t) acc2[t2][t] = 0.f;
        const int n0 = wave * 2 + t2;
#pragma unroll
        for (int kt = 0; kt < 4; ++kt) {
            bfrag bfr = *(const bfrag*)(Wp + ((size_t)(n0 * 4 + kt) * 64 + lane) * 8);
            acc2[t2] = __builtin_amdgcn_mfma_f32_16x16x32_bf16(afr[kt], bfr, acc2[t2], 0, 0, 0);
        }
    }

#pragma unroll
    for (int t2 = 0; t2 < 2; ++t2) {
        const int col = (wave * 2 + t2) * 16 + m;
#pragma unroll
        for (int rr = 0; rr < 4; ++rr) {
            const int row = pnode[q * 4 + rr];
            BW[(size_t)row * 128 + col] = f2bf(acc2[t2][rr]);
        }
    }
}

// ---------------------------------------------------------------------------
// K4: layer-1 gather over BW (deg-sorted via perm).
//   H[n] = bf16( relu( agg*inrm + b_g1 ) )
// ---------------------------------------------------------------------------
__global__ __launch_bounds__(256) void agg1_kernel(
    const uint4* __restrict__ BW,
    const int* __restrict__ bucket, const int2* __restrict__ csrD,
    const float* __restrict__ b_g1,
    const int* __restrict__ perm,
    uint4* __restrict__ H) {
    int idx = blockIdx.x * blockDim.x + threadIdx.x;
    int n = perm[idx >> 4];
    int j8 = idx & 15;
    const int2 cd = csrD[n];
    const int cnt = cd.y;
    const int* bk = bucket + cd.x;
    float acc[8] = {0.f, 0.f, 0.f, 0.f, 0.f, 0.f, 0.f, 0.f};
    int i = 0;
    GATHER8(BW)
    float inr = onrm_of(cnt);
    const float* bg = b_g1 + j8 * 8;
    float r[8];
#pragma unroll
    for (int k = 0; k < 8; ++k)
        r[k] = fmaxf(acc[k] * inr + bg[k], 0.f);
    uint4 o;
    o.x = pack2(r[0], r[1]); o.y = pack2(r[2], r[3]);
    o.z = pack2(r[4], r[5]); o.w = pack2(r[6], r[7]);
    H[(size_t)n * 16 + j8] = o;
}

// ---------------------------------------------------------------------------
// K5: final edge-typed gather (fwd weighted + bwd, deg-sorted) -> fp32 out.
// ---------------------------------------------------------------------------
__global__ __launch_bounds__(256) void final_kernel(
    const uint4* __restrict__ H,
    const int* __restrict__ bucket, const int2* __restrict__ csrD,
    const int* __restrict__ bucketB, const int2* __restrict__ csrB,
    const int* __restrict__ perm,
    float4* __restrict__ out4) {
    int idx = blockIdx.x * blockDim.x + threadIdx.x;
    int n = perm[idx >> 4];
    int j8 = idx & 15;
    float acc[8] = {0.f, 0.f, 0.f, 0.f, 0.f, 0.f, 0.f, 0.f};
    const int2 cd = csrD[n];
    const int cnt = cd.y;
    const int* bk = bucket + cd.x;
    int i = 0;
    for (; i + 8 <= cnt; i += 8) {
        int4 c0 = *(const int4*)(bk + i);
        int4 c1 = *(const int4*)(bk + i + 4);
        int cc[8] = {c0.x, c0.y, c0.z, c0.w, c1.x, c1.y, c1.z, c1.w};
        uint4 v[8];
#pragma unroll
        for (int k = 0; k < 8; ++k)
            v[k] = H[(size_t)(cc[k] & MASK31) * 16 + j8];
#pragma unroll
        for (int k = 0; k < 8; ++k)
            acc8_addw(acc, v[k], (cc[k] < 0) ? 2.0f : 1.0f);
    }
    if (i + 4 <= cnt) {
        int4 c0 = *(const int4*)(bk + i);
        int cc[4] = {c0.x, c0.y, c0.z, c0.w};
        uint4 v[4];
#pragma unroll
        for (int k = 0; k < 4; ++k)
            v[k] = H[(size_t)(cc[k] & MASK31) * 16 + j8];
#pragma unroll
        for (int k = 0; k < 4; ++k)
            acc8_addw(acc, v[k], (cc[k] < 0) ? 2.0f : 1.0f);
        i += 4;
    }
    for (; i < cnt; ++i) {
        int c = bk[i];
        acc8_addw(acc, H[(size_t)(c & MASK31) * 16 + j8], (c < 0) ? 2.0f : 1.0f);
    }
    const int2 cb = csrB[n];
    const int* bkB = bucketB + cb.x;
    for (int k = 0; k < cb.y; ++k)
        acc8_add(acc, H[(size_t)bkB[k] * 16 + j8]);
    float4 o0 = {acc[0], acc[1], acc[2], acc[3]};
    float4 o1 = {acc[4], acc[5], acc[6], acc[7]};
    out4[(size_t)n * 32 + j8 * 2]     = o0;
    out4[(size_t)n * 32 + j8 * 2 + 1] = o1;
}

extern "C" void kernel_launch(void* const* d_in, const int* in_sizes, int n_in,
                              void* d_out, int out_size, void* d_ws, size_t ws_size,
                              hipStream_t stream) {
    const float* feat[4]  = {(const float*)d_in[0], (const float*)d_in[3],
                             (const float*)d_in[6], (const float*)d_in[9]};
    const float* W_fc[4]  = {(const float*)d_in[1], (const float*)d_in[4],
                             (const float*)d_in[7], (const float*)d_in[10]};
    const float* b_fc[4]  = {(const float*)d_in[2], (const float*)d_in[5],
                             (const float*)d_in[8], (const float*)d_in[11]};
    const int*   src      = (const int*)d_in[12];
    const int*   dst      = (const int*)d_in[13];
    const int*   efeat    = (const int*)d_in[14];
    const float* b_g0     = (const float*)d_in[15];
    const float* W_g1     = (const float*)d_in[16];
    const float* b_g1     = (const float*)d_in[17];
    float* out = (float*)d_out;

    // ---- workspace layout, ~49 MB ----
    char* p = (char*)d_ws;
    unsigned short* Abf = (unsigned short*)p; p += (size_t)N_NODES * HDIM * 2;  // 12.8 MB
    unsigned short* Bbf = (unsigned short*)p; p += (size_t)N_NODES * HDIM * 2;  // 12.8 MB
    unsigned short* Wp  = (unsigned short*)p; p += (size_t)65536 * 2;           // 128 KB
    int* bucket  = (int*)p; p += (size_t)(E_EDGES + 4 * N_NODES) * 4; // 3.2 MB (aligned CSR)
    int* bucketB = (int*)p; p += (size_t)E_EDGES * 4;                 // 2.4 MB
    unsigned* partial = (unsigned*)p; p += (size_t)HQD * N_NODES * 4; // 12.8 MB packed
    int* degD  = (int*)p; p += (size_t)N_NODES * 4;              // 200 KB
    int* degB  = (int*)p; p += (size_t)N_NODES * 4;
    int* scanD = (int*)p; p += (size_t)N_NODES * 4;
    int* scanB = (int*)p; p += (size_t)N_NODES * 4;
    int2* csrD = (int2*)p; p += (size_t)N_NODES * 8;             // 400 KB
    int2* csrB = (int2*)p; p += (size_t)N_NODES * 8;
    float* onrm_buf = (float*)p; p += (size_t)N_NODES * 4;
    int* blocksumD = (int*)p; p += 256 * 4;
    int* blocksumB = (int*)p; p += 256 * 4;
    int* binpartT  = (int*)p; p += (size_t)64 * NBLK_NODE * 4;   // 50 KB
    int* perm      = (int*)p; p += (size_t)N_NODES * 4;          // 200 KB

    const unsigned short* Wpg = Wp + 49152;

    // K0: fused packed histogram (one edge pass, 1024 thr) + weight packing
    prep_kernel<<<NBLK_DB + 8, 1024, 0, stream>>>(
        W_fc[0], W_fc[1], W_fc[2], W_fc[3], W_g1, src, dst, efeat,
        Wp, partial);

    // P1: packed plane pass -> deg/onrm; aligned block scan; deg-bin hist
    plane_prefix_kernel<<<NBLK_NODE, 256, 0, stream>>>(
        partial, degD, degB, scanD, scanB, blocksumD, blocksumB, onrm_buf,
        binpartT);

    // P2: base add -> CSR descriptors; build deg-sorted perm
    base_add_kernel<<<NBLK_NODE, 256, 0, stream>>>(
        blocksumD, blocksumB, scanD, scanB, degD, degB, binpartT,
        csrD, csrB, perm);

    // K1: fused counting-sort scatter + 4 FC GEMMs (mem/MFMA overlap)
    scatfc_kernel<<<NBLK_DB + NBLK_FC, 1024, 0, stream>>>(
        src, dst, efeat, partial, csrD, csrB, bucket, bucketB,
        feat[0], feat[1], feat[2], feat[3], Wp,
        b_fc[0], b_fc[1], b_fc[2], b_fc[3], onrm_buf, Abf);

    const int grid_node = (N_NODES * 16) / 256;   // 3125 exact

    // K3: fused layer0 gather + GEMM(W_g1): Abf -> Bbf (BW), deg-sorted
    agg0g_kernel<<<grid_node, 256, 0, stream>>>(
        (const uint4*)Abf, bucket, csrD, onrm_buf, b_g0, Wpg, perm, Bbf);

    // K4: layer1 gather over BW: Bbf -> Abf (H), deg-sorted
    agg1_kernel<<<grid_node, 256, 0, stream>>>(
        (const uint4*)Bbf, bucket, csrD, b_g1, perm, (uint4*)Abf);

    // K5: final edge-typed gather: Abf (H) -> fp32 out, deg-sorted
    final_kernel<<<grid_node, 256, 0, stream>>>(
        (const uint4*)Abf, bucket, csrD, bucketB, csrB, perm, (float4*)out);
}

// Round 11
// 226.475 us; speedup vs baseline: 1.0430x; 1.0430x over previous
//
#include <hip/hip_runtime.h>
#include <hip/hip_bf16.h>

#define N_NODES 50000
#define N_PER   12500
#define E_EDGES 600000
#define HDIM    128

#define NBLK_FC    ((N_PER + 63) / 64)            // 196
#define NBLK_NODE  ((N_NODES + 255) / 256)        // 196
#define MASK31  0x7fffffff

// counting-sort tiling: zero device atomics anywhere.
#define HQD 32                   // edge slices (halved: less partial traffic)
#define HSL_D (E_EDGES / HQD)    // 18750
#define NBLK_DB (HQD * 4)        // 128 scatter/hist blocks

typedef __attribute__((ext_vector_type(8))) short bfrag;   // 8 bf16 (4 VGPRs)
typedef __attribute__((ext_vector_type(4))) float ffrag;   // 4 fp32 acc

__device__ __forceinline__ unsigned short f2bf(float f) {
    union { float f; unsigned u; } x; x.f = f;
    unsigned r = x.u + 0x7fffu + ((x.u >> 16) & 1u);   // RTNE
    return (unsigned short)(r >> 16);
}
__device__ __forceinline__ float lo_bf(unsigned v) { return __uint_as_float(v << 16); }
__device__ __forceinline__ float hi_bf(unsigned v) { return __uint_as_float(v & 0xffff0000u); }
__device__ __forceinline__ unsigned pack2(float a, float b) {
    return (unsigned)f2bf(a) | ((unsigned)f2bf(b) << 16);
}
__device__ __forceinline__ float onrm_of(int deg) {
    return rsqrtf(fmaxf((float)deg, 1.0f));
}

__device__ __forceinline__ void acc8_add(float* acc, uint4 v) {
    acc[0] += lo_bf(v.x); acc[1] += hi_bf(v.x);
    acc[2] += lo_bf(v.y); acc[3] += hi_bf(v.y);
    acc[4] += lo_bf(v.z); acc[5] += hi_bf(v.z);
    acc[6] += lo_bf(v.w); acc[7] += hi_bf(v.w);
}
__device__ __forceinline__ void acc8_addw(float* acc, uint4 v, float w) {
    acc[0] += lo_bf(v.x) * w; acc[1] += hi_bf(v.x) * w;
    acc[2] += lo_bf(v.y) * w; acc[3] += hi_bf(v.y) * w;
    acc[4] += lo_bf(v.z) * w; acc[5] += hi_bf(v.z) * w;
    acc[6] += lo_bf(v.w) * w; acc[7] += hi_bf(v.w) * w;
}

// ---------------------------------------------------------------------------
// K0 prep (1024 threads):
//   blocks [0,128):   fused histogram — ONE packed uint32 plane array:
//                     D (bits 0..9) | B (10..15) | S (16..31). Per-slice
//                     per-node counts <= ~15, so field carries impossible.
//   blocks [128,136): weight fragment packing
// ---------------------------------------------------------------------------
__global__ __launch_bounds__(1024) void prep_kernel(
    const float* __restrict__ W0, const float* __restrict__ W1,
    const float* __restrict__ W2, const float* __restrict__ W3,
    const float* __restrict__ Wg,
    const int* __restrict__ src, const int* __restrict__ dst,
    const int* __restrict__ ef,
    unsigned short* __restrict__ Wp,
    unsigned* __restrict__ partial) {
    __shared__ unsigned hist[N_PER];            // 50 KB
    int b = blockIdx.x;
    if (b < NBLK_DB) {                          // fused D|B|S histogram
        const int q = b >> 2;
        const int p = b & 3;
        const int g0 = p * N_PER;
        for (int j = threadIdx.x; j < N_PER; j += 1024) hist[j] = 0;
        __syncthreads();
        const int e0 = q * HSL_D;
        for (int i = e0 + threadIdx.x; i < e0 + HSL_D; i += 1024) {
            int d = dst[i], t = ef[i], s = src[i];
            unsigned rd = (unsigned)(d - g0);
            if (rd < (unsigned)N_PER) atomicAdd(&hist[rd], 1u);
            unsigned rs = (unsigned)(s - g0);
            if (rs < (unsigned)N_PER) {
                unsigned inc = 0x10000u
                             + ((t == 6 || t == 14 || t == 30) ? 0x400u : 0u);
                atomicAdd(&hist[rs], inc);
            }
        }
        __syncthreads();
        for (int j = threadIdx.x; j < N_PER; j += 1024)
            partial[(size_t)q * N_NODES + g0 + j] = hist[j];
    } else {                                    // weight packing
        int tid = (b - NBLK_DB) * 1024 + threadIdx.x;   // [0, 8192)
        const float* W; int D, base, off;
        if      (tid < 2048) { W = W0; D = 128; base = 0;    off = 0;     }
        else if (tid < 4096) { W = W1; D = 128; base = 2048; off = 16384; }
        else if (tid < 5120) { W = W2; D = 64;  base = 4096; off = 32768; }
        else if (tid < 6144) { W = W3; D = 64;  base = 5120; off = 40960; }
        else                 { W = Wg; D = 128; base = 6144; off = 49152; }
        int t2 = tid - base;
        int KT = D / 32;
        int l = t2 & 63;
        int tt = t2 >> 6;
        int kt = tt % KT, n0 = tt / KT;
        int n = n0 * 16 + (l & 15);
        int kb = kt * 32 + (l >> 4) * 8;
#pragma unroll
        for (int j = 0; j < 8; ++j)
            Wp[(size_t)off + (size_t)t2 * 8 + j] = f2bf(W[(size_t)(kb + j) * 128 + n]);
    }
}

// ---------------------------------------------------------------------------
// P1: ONE pass over the 32 packed planes: in-place rewrite to per-slice
//     exclusive prefixes (relD | relB<<10; S field zeroed), true degD/degB,
//     deg_out sum -> onrm_buf, 16B-ALIGNED block-local scan for D
//     (degA=(deg+3)&~3 -> every CSR segment starts on a 16B boundary),
//     plain scan for B, per-block sums.
// ---------------------------------------------------------------------------
__global__ __launch_bounds__(256) void plane_prefix_kernel(
    unsigned* __restrict__ partial,
    int* __restrict__ degD, int* __restrict__ degB,
    int* __restrict__ scanD, int* __restrict__ scanB,
    int* __restrict__ blocksumD, int* __restrict__ blocksumB,
    float* __restrict__ onrm_buf) {
    const int t = threadIdx.x;
    const int n = blockIdx.x * 256 + t;
    int dA = 0, dD = 0, dB = 0;
    if (n < N_NODES) {
        int runD = 0, runB = 0, dS = 0;
#pragma unroll
        for (int q = 0; q < HQD; ++q) {
            size_t ix = (size_t)q * N_NODES + n;
            unsigned w = partial[ix];
            partial[ix] = (unsigned)runD | ((unsigned)runB << 10);
            runD += (int)(w & 0x3FFu);
            runB += (int)((w >> 10) & 0x3Fu);
            dS   += (int)(w >> 16);
        }
        dD = runD; dB = runB;
        degD[n] = dD; degB[n] = dB;
        onrm_buf[n] = onrm_of(dS);
        dA = (dD + 3) & ~3;                      // 16B-aligned segment size
    }
    __shared__ int sD[256], sB[256];
    sD[t] = dA; sB[t] = dB;
    __syncthreads();
    for (int off = 1; off < 256; off <<= 1) {     // Hillis-Steele inclusive
        int xD = (t >= off) ? sD[t - off] : 0;
        int xB = (t >= off) ? sB[t - off] : 0;
        __syncthreads();
        sD[t] += xD; sB[t] += xB;
        __syncthreads();
    }
    if (n < N_NODES) {
        scanD[n] = sD[t] - dA;                    // block-local exclusive
        scanB[n] = sB[t] - dB;
    }
    if (t == 255) {
        blocksumD[blockIdx.x] = sD[255];
        blocksumB[blockIdx.x] = sB[255];
    }
}

// ---------------------------------------------------------------------------
// P2: add block bases and emit interleaved CSR descriptors
//     csrD[n] = {abs base (16B-aligned), true deg}; csrB likewise.
// ---------------------------------------------------------------------------
__global__ __launch_bounds__(256) void base_add_kernel(
    const int* __restrict__ blocksumD, const int* __restrict__ blocksumB,
    const int* __restrict__ scanD, const int* __restrict__ scanB,
    const int* __restrict__ degD, const int* __restrict__ degB,
    int2* __restrict__ csrD, int2* __restrict__ csrB) {
    __shared__ int sD[256], sB[256];
    const int t = threadIdx.x;
    const int bid = blockIdx.x;
    sD[t] = (t < bid) ? blocksumD[t] : 0;
    sB[t] = (t < bid) ? blocksumB[t] : 0;
    __syncthreads();
    for (int off = 128; off >= 1; off >>= 1) {
        if (t < off) { sD[t] += sD[t + off]; sB[t] += sB[t + off]; }
        __syncthreads();
    }
    const int n = bid * 256 + t;
    if (n < N_NODES) {
        csrD[n] = make_int2(scanD[n] + sD[0], degD[n]);
        csrB[n] = make_int2(scanB[n] + sB[0], degB[n]);
    }
}

// ---------------------------------------------------------------------------
// FC MFMA body: out = bf16( (X(rows x D) @ W + bias) * onrm[row] ); X fp32.
// tid must be in [0,256). No LDS, no sync — safe inside mixed blocks.
// ---------------------------------------------------------------------------
template<int D>
__device__ __forceinline__ void fc_body(
    int blk, int tid,
    const float* __restrict__ X,
    const unsigned short* __restrict__ Wp,
    const float* __restrict__ bias,
    const float* __restrict__ onrm,
    unsigned short* __restrict__ outbf,
    int rows)
{
    constexpr int KT = D / 32;
    const int lane = tid & 63;
    const int wave = tid >> 6;
    const int m = lane & 15, q = lane >> 4;
    const int rbase = blk * 64 + wave * 16;
    const int row = rbase + m;

    bfrag afr[KT];
#pragma unroll
    for (int kt = 0; kt < KT; ++kt) {
        bfrag a;
        if (row < rows) {
            const float* xp = X + (size_t)row * D + kt * 32 + q * 8;
            float4 u0 = *(const float4*)xp;
            float4 u1 = *(const float4*)(xp + 4);
            a[0] = (short)f2bf(u0.x); a[1] = (short)f2bf(u0.y);
            a[2] = (short)f2bf(u0.z); a[3] = (short)f2bf(u0.w);
            a[4] = (short)f2bf(u1.x); a[5] = (short)f2bf(u1.y);
            a[6] = (short)f2bf(u1.z); a[7] = (short)f2bf(u1.w);
        } else {
#pragma unroll
            for (int t = 0; t < 8; ++t) a[t] = 0;
        }
        afr[kt] = a;
    }

    ffrag acc[8];
#pragma unroll
    for (int n0 = 0; n0 < 8; ++n0)
#pragma unroll
        for (int t = 0; t < 4; ++t) acc[n0][t] = 0.f;

#pragma unroll
    for (int n0 = 0; n0 < 8; ++n0)
#pragma unroll
        for (int kt = 0; kt < KT; ++kt) {
            bfrag bfr = *(const bfrag*)(Wp + ((size_t)(n0 * KT + kt) * 64 + lane) * 8);
            acc[n0] = __builtin_amdgcn_mfma_f32_16x16x32_bf16(afr[kt], bfr, acc[n0], 0, 0, 0);
        }

#pragma unroll
    for (int n0 = 0; n0 < 8; ++n0) {
        const int col = n0 * 16 + m;
        const float bj = bias[col];
#pragma unroll
        for (int r = 0; r < 4; ++r) {
            int orow = rbase + q * 4 + r;
            if (orow < rows)
                outbf[(size_t)orow * 128 + col] =
                    f2bf((acc[n0][r] + bj) * onrm[orow]);
        }
    }
}

// ---------------------------------------------------------------------------
// K1: fused scatter + FC. 1024-thread blocks.
//   blocks [0,128):   counting-sort scatter (LDS atomics, 50 KB offP;
//                     offP = abs 16B-aligned D slot (20b) | relB (12b))
//   blocks [128,324): 4 FC 64-row tiles each (tid>>8 selects tile).
// ---------------------------------------------------------------------------
__global__ __launch_bounds__(1024) void scatfc_kernel(
    const int* __restrict__ src, const int* __restrict__ dst,
    const int* __restrict__ ef,
    const unsigned* __restrict__ partial,
    const int2* __restrict__ csrD, const int2* __restrict__ csrB,
    int* __restrict__ bucket, int* __restrict__ bucketB,
    const float* __restrict__ f0, const float* __restrict__ f1,
    const float* __restrict__ f2, const float* __restrict__ f3,
    const unsigned short* __restrict__ Wp,
    const float* __restrict__ b0, const float* __restrict__ b1,
    const float* __restrict__ b2, const float* __restrict__ b3,
    const float* __restrict__ onrm_buf,
    unsigned short* __restrict__ Abf)
{
    __shared__ unsigned offP[N_PER];   // absD (20b) | relB (12b)
    const int b = blockIdx.x;
    if (b < NBLK_DB) {
        const int q = b >> 2;
        const int p = b & 3;
        const int g0 = p * N_PER;
        for (int j = threadIdx.x; j < N_PER; j += 1024) {
            unsigned w = partial[(size_t)q * N_NODES + g0 + j];
            offP[j] = (unsigned)(csrD[g0 + j].x + (int)(w & 0x3FFu))
                    | (((w >> 10) & 0x3Fu) << 20);
        }
        __syncthreads();
        const int e0 = q * HSL_D;
        for (int i = e0 + threadIdx.x; i < e0 + HSL_D; i += 1024) {
            int s = src[i], d = dst[i], t = ef[i];
            unsigned rd = (unsigned)(d - g0);
            if (rd < (unsigned)N_PER) {
                unsigned old = atomicAdd(&offP[rd], 1u);          // LDS atomic
                bucket[old & 0xFFFFFu] = s | ((t <= 4) ? 0x80000000 : 0);
            }
            if (t == 6 || t == 14 || t == 30) {
                unsigned rs = (unsigned)(s - g0);
                if (rs < (unsigned)N_PER) {
                    unsigned old = atomicAdd(&offP[rs], 1u << 20);
                    bucketB[csrB[s].x + (int)(old >> 20)] = d;
                }
            }
        }
    } else {
        int ft = (b - NBLK_DB) * 4 + (threadIdx.x >> 8);   // 0..783
        int tid = threadIdx.x & 255;
        int which = ft / NBLK_FC;
        int blk = ft - which * NBLK_FC;
        if (which == 0)
            fc_body<128>(blk, tid, f0, Wp,         b0, onrm_buf,
                         Abf + (size_t)0 * N_PER * HDIM, N_PER);
        else if (which == 1)
            fc_body<128>(blk, tid, f1, Wp + 16384, b1, onrm_buf + N_PER,
                         Abf + (size_t)1 * N_PER * HDIM, N_PER);
        else if (which == 2)
            fc_body<64>(blk, tid, f2, Wp + 32768, b2, onrm_buf + 2 * N_PER,
                        Abf + (size_t)2 * N_PER * HDIM, N_PER);
        else
            fc_body<64>(blk, tid, f3, Wp + 40960, b3, onrm_buf + 3 * N_PER,
                        Abf + (size_t)3 * N_PER * HDIM, N_PER);
    }
}

// ---------------------------------------------------------------------------
// Gather core: 16B-aligned CSR base -> int4 index loads (2 per 8 edges).
// ---------------------------------------------------------------------------
#define GATHER8(DSTARR)                                                       \
    for (; i + 8 <= cnt; i += 8) {                                            \
        int4 c0 = *(const int4*)(bk + i);                                     \
        int4 c1 = *(const int4*)(bk + i + 4);                                 \
        int cc[8] = {c0.x, c0.y, c0.z, c0.w, c1.x, c1.y, c1.z, c1.w};         \
        uint4 v[8];                                                           \
        _Pragma("unroll")                                                     \
        for (int k = 0; k < 8; ++k)                                           \
            v[k] = DSTARR[(size_t)(cc[k] & MASK31) * 16 + j8];                \
        _Pragma("unroll")                                                     \
        for (int k = 0; k < 8; ++k) acc8_add(acc, v[k]);                      \
    }                                                                         \
    if (i + 4 <= cnt) {                                                       \
        int4 c0 = *(const int4*)(bk + i);                                     \
        int cc[4] = {c0.x, c0.y, c0.z, c0.w};                                 \
        uint4 v[4];                                                           \
        _Pragma("unroll")                                                     \
        for (int k = 0; k < 4; ++k)                                           \
            v[k] = DSTARR[(size_t)(cc[k] & MASK31) * 16 + j8];                \
        _Pragma("unroll")                                                     \
        for (int k = 0; k < 4; ++k) acc8_add(acc, v[k]);                      \
        i += 4;                                                               \
    }                                                                         \
    for (; i < cnt; ++i)                                                      \
        acc8_add(acc, DSTARR[(size_t)(bk[i] & MASK31) * 16 + j8]);

// ---------------------------------------------------------------------------
// K3: FUSED layer-0 gather + dense GEMM with W_g1 (agg/matmul commute).
//   Block = 16 nodes (identity order: sequential CSR reads, coalesced writes).
//   Writes BW = B @ W_g1 directly.
// ---------------------------------------------------------------------------
__global__ __launch_bounds__(256) void agg0g_kernel(
    const uint4* __restrict__ A,
    const int* __restrict__ bucket, const int2* __restrict__ csrD,
    const float* __restrict__ onrm_buf, const float* __restrict__ b_g0,
    const unsigned short* __restrict__ Wp,
    unsigned short* __restrict__ BW) {
    __shared__ uint4 Bt[256];          // 4 KB: idx = j8*16 + node_local
    const int tdx = threadIdx.x;
    const int nloc = tdx >> 4, j8 = tdx & 15;
    const int n = blockIdx.x * 16 + nloc;

    const int2 cd = csrD[n];
    const int cnt = cd.y;
    const int* bk = bucket + cd.x;
    float acc[8] = {0.f, 0.f, 0.f, 0.f, 0.f, 0.f, 0.f, 0.f};
    int i = 0;
    GATHER8(A)

    float inr = onrm_of(cnt);
    float onr = onrm_buf[n];
    const float* bg = b_g0 + j8 * 8;
    float r[8];
#pragma unroll
    for (int k = 0; k < 8; ++k)
        r[k] = fmaxf(acc[k] * inr + bg[k], 0.f) * onr;
    uint4 o;
    o.x = pack2(r[0], r[1]); o.y = pack2(r[2], r[3]);
    o.z = pack2(r[4], r[5]); o.w = pack2(r[6], r[7]);
    Bt[j8 * 16 + nloc] = o;
    __syncthreads();

    // MFMA phase: wave w -> col tiles n0 = 2w, 2w+1
    const int lane = tdx & 63;
    const int wave = tdx >> 6;
    const int m = lane & 15, q = lane >> 4;

    bfrag afr[4];
#pragma unroll
    for (int kt = 0; kt < 4; ++kt)
        afr[kt] = *(const bfrag*)(Bt + (kt * 4 + q) * 16 + m);

    ffrag acc2[2];
#pragma unroll
    for (int t2 = 0; t2 < 2; ++t2) {
#pragma unroll
        for (int t = 0; t < 4; ++t) acc2[t2][t] = 0.f;
        const int n0 = wave * 2 + t2;
#pragma unroll
        for (int kt = 0; kt < 4; ++kt) {
            bfrag bfr = *(const bfrag*)(Wp + ((size_t)(n0 * 4 + kt) * 64 + lane) * 8);
            acc2[t2] = __builtin_amdgcn_mfma_f32_16x16x32_bf16(afr[kt], bfr, acc2[t2], 0, 0, 0);
        }
    }

    const int rowbase = blockIdx.x * 16;
#pragma unroll
    for (int t2 = 0; t2 < 2; ++t2) {
        const int col = (wave * 2 + t2) * 16 + m;
#pragma unroll
        for (int rr = 0; rr < 4; ++rr) {
            const int row = rowbase + q * 4 + rr;
            BW[(size_t)row * 128 + col] = f2bf(acc2[t2][rr]);
        }
    }
}

// ---------------------------------------------------------------------------
// K4: layer-1 gather over BW.  H[n] = bf16( relu( agg*inrm + b_g1 ) )
// ---------------------------------------------------------------------------
__global__ __launch_bounds__(256) void agg1_kernel(
    const uint4* __restrict__ BW,
    const int* __restrict__ bucket, const int2* __restrict__ csrD,
    const float* __restrict__ b_g1,
    uint4* __restrict__ H) {
    int idx = blockIdx.x * blockDim.x + threadIdx.x;
    int n = idx >> 4, j8 = idx & 15;
    const int2 cd = csrD[n];
    const int cnt = cd.y;
    const int* bk = bucket + cd.x;
    float acc[8] = {0.f, 0.f, 0.f, 0.f, 0.f, 0.f, 0.f, 0.f};
    int i = 0;
    GATHER8(BW)
    float inr = onrm_of(cnt);
    const float* bg = b_g1 + j8 * 8;
    float r[8];
#pragma unroll
    for (int k = 0; k < 8; ++k)
        r[k] = fmaxf(acc[k] * inr + bg[k], 0.f);
    uint4 o;
    o.x = pack2(r[0], r[1]); o.y = pack2(r[2], r[3]);
    o.z = pack2(r[4], r[5]); o.w = pack2(r[6], r[7]);
    H[(size_t)n * 16 + j8] = o;
}

// ---------------------------------------------------------------------------
// K5: final edge-typed gather (fwd weighted + bwd) -> fp32 out.
// ---------------------------------------------------------------------------
__global__ __launch_bounds__(256) void final_kernel(
    const uint4* __restrict__ H,
    const int* __restrict__ bucket, const int2* __restrict__ csrD,
    const int* __restrict__ bucketB, const int2* __restrict__ csrB,
    float4* __restrict__ out4) {
    int idx = blockIdx.x * blockDim.x + threadIdx.x;
    int n = idx >> 4, j8 = idx & 15;
    float acc[8] = {0.f, 0.f, 0.f, 0.f, 0.f, 0.f, 0.f, 0.f};
    const int2 cd = csrD[n];
    const int cnt = cd.y;
    const int* bk = bucket + cd.x;
    int i = 0;
    for (; i + 8 <= cnt; i += 8) {
        int4 c0 = *(const int4*)(bk + i);
        int4 c1 = *(const int4*)(bk + i + 4);
        int cc[8] = {c0.x, c0.y, c0.z, c0.w, c1.x, c1.y, c1.z, c1.w};
        uint4 v[8];
#pragma unroll
        for (int k = 0; k < 8; ++k)
            v[k] = H[(size_t)(cc[k] & MASK31) * 16 + j8];
#pragma unroll
        for (int k = 0; k < 8; ++k)
            acc8_addw(acc, v[k], (cc[k] < 0) ? 2.0f : 1.0f);
    }
    if (i + 4 <= cnt) {
        int4 c0 = *(const int4*)(bk + i);
        int cc[4] = {c0.x, c0.y, c0.z, c0.w};
        uint4 v[4];
#pragma unroll
        for (int k = 0; k < 4; ++k)
            v[k] = H[(size_t)(cc[k] & MASK31) * 16 + j8];
#pragma unroll
        for (int k = 0; k < 4; ++k)
            acc8_addw(acc, v[k], (cc[k] < 0) ? 2.0f : 1.0f);
        i += 4;
    }
    for (; i < cnt; ++i) {
        int c = bk[i];
        acc8_addw(acc, H[(size_t)(c & MASK31) * 16 + j8], (c < 0) ? 2.0f : 1.0f);
    }
    const int2 cb = csrB[n];
    const int* bkB = bucketB + cb.x;
    for (int k = 0; k < cb.y; ++k)
        acc8_add(acc, H[(size_t)bkB[k] * 16 + j8]);
    float4 o0 = {acc[0], acc[1], acc[2], acc[3]};
    float4 o1 = {acc[4], acc[5], acc[6], acc[7]};
    out4[(size_t)n * 32 + j8 * 2]     = o0;
    out4[(size_t)n * 32 + j8 * 2 + 1] = o1;
}

extern "C" void kernel_launch(void* const* d_in, const int* in_sizes, int n_in,
                              void* d_out, int out_size, void* d_ws, size_t ws_size,
                              hipStream_t stream) {
    const float* feat[4]  = {(const float*)d_in[0], (const float*)d_in[3],
                             (const float*)d_in[6], (const float*)d_in[9]};
    const float* W_fc[4]  = {(const float*)d_in[1], (const float*)d_in[4],
                             (const float*)d_in[7], (const float*)d_in[10]};
    const float* b_fc[4]  = {(const float*)d_in[2], (const float*)d_in[5],
                             (const float*)d_in[8], (const float*)d_in[11]};
    const int*   src      = (const int*)d_in[12];
    const int*   dst      = (const int*)d_in[13];
    const int*   efeat    = (const int*)d_in[14];
    const float* b_g0     = (const float*)d_in[15];
    const float* W_g1     = (const float*)d_in[16];
    const float* b_g1     = (const float*)d_in[17];
    float* out = (float*)d_out;

    // ---- workspace layout, ~42 MB ----
    char* p = (char*)d_ws;
    unsigned short* Abf = (unsigned short*)p; p += (size_t)N_NODES * HDIM * 2;  // 12.8 MB
    unsigned short* Bbf = (unsigned short*)p; p += (size_t)N_NODES * HDIM * 2;  // 12.8 MB
    unsigned short* Wp  = (unsigned short*)p; p += (size_t)65536 * 2;           // 128 KB
    int* bucket  = (int*)p; p += (size_t)(E_EDGES + 4 * N_NODES) * 4; // 3.2 MB (aligned CSR)
    int* bucketB = (int*)p; p += (size_t)E_EDGES * 4;                 // 2.4 MB
    unsigned* partial = (unsigned*)p; p += (size_t)HQD * N_NODES * 4; // 6.4 MB packed
    int* degD  = (int*)p; p += (size_t)N_NODES * 4;              // 200 KB
    int* degB  = (int*)p; p += (size_t)N_NODES * 4;
    int* scanD = (int*)p; p += (size_t)N_NODES * 4;
    int* scanB = (int*)p; p += (size_t)N_NODES * 4;
    int2* csrD = (int2*)p; p += (size_t)N_NODES * 8;             // 400 KB
    int2* csrB = (int2*)p; p += (size_t)N_NODES * 8;
    float* onrm_buf = (float*)p; p += (size_t)N_NODES * 4;
    int* blocksumD = (int*)p; p += 256 * 4;
    int* blocksumB = (int*)p; p += 256 * 4;

    const unsigned short* Wpg = Wp + 49152;

    // K0: fused packed histogram (one edge pass, 1024 thr) + weight packing
    prep_kernel<<<NBLK_DB + 8, 1024, 0, stream>>>(
        W_fc[0], W_fc[1], W_fc[2], W_fc[3], W_g1, src, dst, efeat,
        Wp, partial);

    // P1: single packed plane pass -> deg/onrm; aligned block scan
    plane_prefix_kernel<<<NBLK_NODE, 256, 0, stream>>>(
        partial, degD, degB, scanD, scanB, blocksumD, blocksumB, onrm_buf);

    // P2: base add -> interleaved CSR descriptors
    base_add_kernel<<<NBLK_NODE, 256, 0, stream>>>(
        blocksumD, blocksumB, scanD, scanB, degD, degB, csrD, csrB);

    // K1: fused counting-sort scatter + 4 FC GEMMs (mem/MFMA overlap)
    scatfc_kernel<<<NBLK_DB + NBLK_FC, 1024, 0, stream>>>(
        src, dst, efeat, partial, csrD, csrB, bucket, bucketB,
        feat[0], feat[1], feat[2], feat[3], Wp,
        b_fc[0], b_fc[1], b_fc[2], b_fc[3], onrm_buf, Abf);

    const int grid_node = (N_NODES * 16) / 256;   // 3125 exact

    // K3: fused layer0 gather + GEMM(W_g1): Abf -> Bbf (BW)
    agg0g_kernel<<<grid_node, 256, 0, stream>>>(
        (const uint4*)Abf, bucket, csrD, onrm_buf, b_g0, Wpg, Bbf);

    // K4: layer1 gather over BW: Bbf -> Abf (H)
    agg1_kernel<<<grid_node, 256, 0, stream>>>(
        (const uint4*)Bbf, bucket, csrD, b_g1, (uint4*)Abf);

    // K5: final edge-typed gather: Abf (H) -> fp32 out
    final_kernel<<<grid_node, 256, 0, stream>>>(
        (const uint4*)Abf, bucket, csrD, bucketB, csrB, (float4*)out);
}